// Round 1
// baseline (50.927 us; speedup 1.0000x reference)
//
#include <hip/hip_runtime.h>

// LIF forward: x [T=32, B=64, N=16384] f32 -> spikes (0/1) f32, same shape.
// mem_{t} = mem_{t-1}*0.25 + x_t ; s_t = (mem_t > 1) ; mem_t *= (1 - s_t)
// All ops bit-exact vs numpy (0.25 multiply is exact; reset is exact).
// Memory-bound streaming kernel: 268 MB total traffic, ~43 us roofline.

__global__ __launch_bounds__(256) void lif_fwd_kernel(
    const float4* __restrict__ x, float4* __restrict__ out, int BN4, int T) {
    const int i = blockIdx.x * blockDim.x + threadIdx.x;
    if (i >= BN4) return;

    const float4* xp = x + i;
    float4* op = out + i;

    float mx = 0.f, my = 0.f, mz = 0.f, mw = 0.f;

    // T is 32 for this problem; unroll fully so loads can be scheduled early.
    #pragma unroll 32
    for (int t = 0; t < T; ++t) {
        const float4 xt = xp[(size_t)t * (size_t)BN4];

        float4 s;
        mx = mx * 0.25f + xt.x;
        my = my * 0.25f + xt.y;
        mz = mz * 0.25f + xt.z;
        mw = mw * 0.25f + xt.w;

        s.x = (mx > 1.0f) ? 1.0f : 0.0f;
        s.y = (my > 1.0f) ? 1.0f : 0.0f;
        s.z = (mz > 1.0f) ? 1.0f : 0.0f;
        s.w = (mw > 1.0f) ? 1.0f : 0.0f;

        // hard reset: spike -> mem = 0, else unchanged (exact)
        mx = (s.x != 0.0f) ? 0.0f : mx;
        my = (s.y != 0.0f) ? 0.0f : my;
        mz = (s.z != 0.0f) ? 0.0f : mz;
        mw = (s.w != 0.0f) ? 0.0f : mw;

        op[(size_t)t * (size_t)BN4] = s;
    }
}

extern "C" void kernel_launch(void* const* d_in, const int* in_sizes, int n_in,
                              void* d_out, int out_size, void* d_ws, size_t ws_size,
                              hipStream_t stream) {
    const float* x = (const float*)d_in[0];
    float* out = (float*)d_out;

    const int T = 32;
    const int total = in_sizes[0];        // 32*64*16384 = 33,554,432
    const int BN = total / T;             // 1,048,576
    const int BN4 = BN / 4;               // 262,144

    const int block = 256;
    const int grid = (BN4 + block - 1) / block;  // 1024

    lif_fwd_kernel<<<grid, block, 0, stream>>>(
        (const float4*)x, (float4*)out, BN4, T);
}